// Round 1
// baseline (1495.449 us; speedup 1.0000x reference)
//
#include <hip/hip_runtime.h>

#define BEPS 1e-5f
static constexpr int TPB = 256;

// ---------------- CSR build ----------------

__global__ __launch_bounds__(TPB) void k_zero_int(int* __restrict__ p, int n) {
  int i = blockIdx.x * TPB + threadIdx.x;
  if (i < n) p[i] = 0;
}

__global__ __launch_bounds__(TPB) void k_count(const int* __restrict__ dst,
                                               int* __restrict__ cnt, int E) {
  int e = blockIdx.x * TPB + threadIdx.x;
  if (e < E) atomicAdd(&cnt[dst[e]], 1);
}

__global__ __launch_bounds__(TPB) void k_dinv(const int* __restrict__ cnt,
                                              float* __restrict__ dinv, int N) {
  int i = blockIdx.x * TPB + threadIdx.x;
  if (i < N) dinv[i] = rsqrtf((float)(cnt[i] + 1));  // deg = in-degree + 1 (self loop)
}

__global__ __launch_bounds__(TPB) void k_blocksum(const int* __restrict__ cnt,
                                                  int* __restrict__ bsum, int N) {
  __shared__ int sh[TPB];
  int i = blockIdx.x * TPB + threadIdx.x;
  int t = threadIdx.x;
  sh[t] = (i < N) ? cnt[i] : 0;
  __syncthreads();
  for (int s = TPB / 2; s > 0; s >>= 1) {
    if (t < s) sh[t] += sh[t + s];
    __syncthreads();
  }
  if (t == 0) bsum[blockIdx.x] = sh[0];
}

// single block exclusive scan of up to 512 block sums (gN = 391 for N=100000)
__global__ __launch_bounds__(512) void k_scan_bsum(const int* __restrict__ bsum,
                                                   int* __restrict__ boff, int nb) {
  __shared__ int sh[512];
  int t = threadIdx.x;
  int v = (t < nb) ? bsum[t] : 0;
  sh[t] = v;
  __syncthreads();
  for (int s = 1; s < 512; s <<= 1) {
    int x = sh[t];
    int y = (t >= s) ? sh[t - s] : 0;
    __syncthreads();
    sh[t] = x + y;
    __syncthreads();
  }
  if (t < nb) boff[t] = sh[t] - v;  // exclusive
}

__global__ __launch_bounds__(TPB) void k_scan_final(const int* __restrict__ cnt,
                                                    const int* __restrict__ boff,
                                                    int* __restrict__ row_ptr, int N) {
  __shared__ int sh[TPB];
  int i = blockIdx.x * TPB + threadIdx.x;
  int t = threadIdx.x;
  int v = (i < N) ? cnt[i] : 0;
  sh[t] = v;
  __syncthreads();
  for (int s = 1; s < TPB; s <<= 1) {
    int x = sh[t];
    int y = (t >= s) ? sh[t - s] : 0;
    __syncthreads();
    sh[t] = x + y;
    __syncthreads();
  }
  if (i < N) row_ptr[i + 1] = boff[blockIdx.x] + sh[t];  // inclusive -> row_ptr[i+1]
  if (i == 0) row_ptr[0] = 0;
}

__global__ __launch_bounds__(TPB) void k_copy_int(const int* __restrict__ a,
                                                  int* __restrict__ b, int n) {
  int i = blockIdx.x * TPB + threadIdx.x;
  if (i < n) b[i] = a[i];
}

__global__ __launch_bounds__(TPB) void k_fill(const int* __restrict__ src,
                                              const int* __restrict__ dst,
                                              int* __restrict__ pos,
                                              int* __restrict__ col, int E) {
  int e = blockIdx.x * TPB + threadIdx.x;
  if (e < E) {
    int d = dst[e];
    int p = atomicAdd(&pos[d], 1);
    col[p] = src[e];
  }
}

// ---------------- per-layer kernels ----------------

// xw'[n][fo] = dinv[n] * sum_k h[n][k] * W[k][fo]
template <int FI, int FO>
__global__ __launch_bounds__(TPB) void k_gemm(const float* __restrict__ h,
                                              const float* __restrict__ W,
                                              const float* __restrict__ dinv,
                                              float* __restrict__ out, int N) {
  __shared__ float Ws[FI * FO];
  for (int i = threadIdx.x; i < FI * FO; i += TPB) Ws[i] = W[i];
  __syncthreads();
  constexpr int RPB = TPB / FO;
  int row = blockIdx.x * RPB + (int)(threadIdx.x / FO);
  int col = threadIdx.x % FO;
  if (row >= N) return;
  const float4* h4 = reinterpret_cast<const float4*>(h + (size_t)row * FI);
  float acc = 0.f;
#pragma unroll
  for (int k4 = 0; k4 < FI / 4; ++k4) {
    float4 hv = h4[k4];
    acc = fmaf(hv.x, Ws[(k4 * 4 + 0) * FO + col], acc);
    acc = fmaf(hv.y, Ws[(k4 * 4 + 1) * FO + col], acc);
    acc = fmaf(hv.z, Ws[(k4 * 4 + 2) * FO + col], acc);
    acc = fmaf(hv.w, Ws[(k4 * 4 + 3) * FO + col], acc);
  }
  out[(size_t)row * FO + col] = acc * dinv[row];
}

// out[d][f] = act( dinv[d]*(xw'[d][f] + sum_{s in N(d)} xw'[s][f]) [+bias / BN / relu] )
template <int F, bool BN>
__global__ __launch_bounds__(TPB) void k_agg(const float* __restrict__ xw,
                                             const int* __restrict__ row_ptr,
                                             const int* __restrict__ colidx,
                                             const float* __restrict__ dinv,
                                             const float* __restrict__ bias,
                                             const float* __restrict__ g,
                                             const float* __restrict__ be,
                                             const float* __restrict__ m,
                                             const float* __restrict__ v,
                                             float* __restrict__ out, int N) {
  constexpr int NPB = TPB / F;
  int node = blockIdx.x * NPB + (int)(threadIdx.x / F);
  int f = threadIdx.x % F;
  if (node >= N) return;
  int e0 = row_ptr[node];
  int e1 = row_ptr[node + 1];
  float acc = xw[(size_t)node * F + f];  // self-loop term (already *dinv[node])
  for (int e = e0; e < e1; ++e) {
    int s = colidx[e];
    acc += xw[(size_t)s * F + f];
  }
  float val = acc * dinv[node];
  if (BN) {
    float sc = g[f] * rsqrtf(v[f] + BEPS);
    val = (val + bias[f] - m[f]) * sc + be[f];
    val = fmaxf(val, 0.f);
  } else {
    val += bias[f];
  }
  out[(size_t)node * F + f] = val;
}

// ---------------- launch ----------------

extern "C" void kernel_launch(void* const* d_in, const int* in_sizes, int n_in,
                              void* d_out, int out_size, void* d_ws, size_t ws_size,
                              hipStream_t stream) {
  const float* x = (const float*)d_in[0];
  const int* ei = (const int*)d_in[1];
  const int N = in_sizes[0] / 128;
  const int E = in_sizes[1] / 2;
  const int* src = ei;
  const int* dst = ei + E;

  const float* w1 = (const float*)d_in[2];  const float* b1 = (const float*)d_in[3];
  const float* w2 = (const float*)d_in[4];  const float* b2 = (const float*)d_in[5];
  const float* w3 = (const float*)d_in[6];  const float* b3 = (const float*)d_in[7];
  const float* w4 = (const float*)d_in[8];  const float* b4 = (const float*)d_in[9];
  const float* w5 = (const float*)d_in[10]; const float* b5 = (const float*)d_in[11];
  const float* g1 = (const float*)d_in[12]; const float* be1 = (const float*)d_in[13];
  const float* m1 = (const float*)d_in[14]; const float* v1 = (const float*)d_in[15];
  const float* g2 = (const float*)d_in[16]; const float* be2 = (const float*)d_in[17];
  const float* m2 = (const float*)d_in[18]; const float* v2 = (const float*)d_in[19];
  const float* g3 = (const float*)d_in[20]; const float* be3 = (const float*)d_in[21];
  const float* m3 = (const float*)d_in[22]; const float* v3 = (const float*)d_in[23];
  const float* g4 = (const float*)d_in[24]; const float* be4 = (const float*)d_in[25];
  const float* m4 = (const float*)d_in[26]; const float* v4 = (const float*)d_in[27];
  float* out = (float*)d_out;

  char* ws = (char*)d_ws;
  size_t off = 0;
  auto alloc = [&](size_t bytes) -> void* {
    void* p = ws + off;
    off += (bytes + 255) & ~(size_t)255;
    return p;
  };
  float* dinv   = (float*)alloc((size_t)N * 4);
  int*   cnt    = (int*)  alloc((size_t)N * 4);
  int*   rowptr = (int*)  alloc((size_t)(N + 1) * 4);
  int*   bsum   = (int*)  alloc(512 * 4);
  int*   boff   = (int*)  alloc(512 * 4);
  int*   colidx = (int*)  alloc((size_t)E * 4);
  float* bufA   = (float*)alloc((size_t)N * 128 * 4);
  float* bufB   = (float*)alloc((size_t)N * 128 * 4);
  (void)ws_size; (void)n_in; (void)out_size;

  int gN = (N + TPB - 1) / TPB;  // 391 for N=100000 (fits single-block scan of 512)
  int gE = (E + TPB - 1) / TPB;

  // CSR build (once per call; int atomics only)
  k_zero_int<<<gN, TPB, 0, stream>>>(cnt, N);
  k_count<<<gE, TPB, 0, stream>>>(dst, cnt, E);
  k_dinv<<<gN, TPB, 0, stream>>>(cnt, dinv, N);
  k_blocksum<<<gN, TPB, 0, stream>>>(cnt, bsum, N);
  k_scan_bsum<<<1, 512, 0, stream>>>(bsum, boff, gN);
  k_scan_final<<<gN, TPB, 0, stream>>>(cnt, boff, rowptr, N);
  k_copy_int<<<gN, TPB, 0, stream>>>(rowptr, cnt, N);
  k_fill<<<gE, TPB, 0, stream>>>(src, dst, cnt, colidx, E);

  // layer 1: 128 -> 64
  k_gemm<128, 64><<<(N + 3) / 4, TPB, 0, stream>>>(x, w1, dinv, bufB, N);
  k_agg<64, true><<<(N + 3) / 4, TPB, 0, stream>>>(bufB, rowptr, colidx, dinv, b1, g1, be1, m1, v1, bufA, N);
  // layer 2: 64 -> 128
  k_gemm<64, 128><<<(N + 1) / 2, TPB, 0, stream>>>(bufA, w2, dinv, bufB, N);
  k_agg<128, true><<<(N + 1) / 2, TPB, 0, stream>>>(bufB, rowptr, colidx, dinv, b2, g2, be2, m2, v2, bufA, N);
  // layer 3: 128 -> 64
  k_gemm<128, 64><<<(N + 3) / 4, TPB, 0, stream>>>(bufA, w3, dinv, bufB, N);
  k_agg<64, true><<<(N + 3) / 4, TPB, 0, stream>>>(bufB, rowptr, colidx, dinv, b3, g3, be3, m3, v3, bufA, N);
  // layer 4: 64 -> 32
  k_gemm<64, 32><<<(N + 7) / 8, TPB, 0, stream>>>(bufA, w4, dinv, bufB, N);
  k_agg<32, true><<<(N + 7) / 8, TPB, 0, stream>>>(bufB, rowptr, colidx, dinv, b4, g4, be4, m4, v4, bufA, N);
  // layer 5: 32 -> 16 (no BN/ReLU), write straight to d_out
  k_gemm<32, 16><<<(N + 15) / 16, TPB, 0, stream>>>(bufA, w5, dinv, bufB, N);
  k_agg<16, false><<<(N + 15) / 16, TPB, 0, stream>>>(bufB, rowptr, colidx, dinv, b5, nullptr, nullptr, nullptr, nullptr, out, N);
}

// Round 2
// 700.250 us; speedup vs baseline: 2.1356x; 2.1356x over previous
//
#include <hip/hip_runtime.h>

#define BEPS 1e-5f
static constexpr int TPB = 256;

// ---------------- CSR build ----------------

__global__ __launch_bounds__(TPB) void k_zero_int(int* __restrict__ p, int n) {
  int i = blockIdx.x * TPB + threadIdx.x;
  if (i < n) p[i] = 0;
}

__global__ __launch_bounds__(TPB) void k_count(const int* __restrict__ dst,
                                               int* __restrict__ cnt, int E) {
  int e = blockIdx.x * TPB + threadIdx.x;
  if (e < E) atomicAdd(&cnt[dst[e]], 1);
}

__global__ __launch_bounds__(TPB) void k_dinv(const int* __restrict__ cnt,
                                              float* __restrict__ dinv, int N) {
  int i = blockIdx.x * TPB + threadIdx.x;
  if (i < N) dinv[i] = rsqrtf((float)(cnt[i] + 1));  // deg = in-degree + 1 (self loop)
}

__global__ __launch_bounds__(TPB) void k_blocksum(const int* __restrict__ cnt,
                                                  int* __restrict__ bsum, int N) {
  __shared__ int sh[TPB];
  int i = blockIdx.x * TPB + threadIdx.x;
  int t = threadIdx.x;
  sh[t] = (i < N) ? cnt[i] : 0;
  __syncthreads();
  for (int s = TPB / 2; s > 0; s >>= 1) {
    if (t < s) sh[t] += sh[t + s];
    __syncthreads();
  }
  if (t == 0) bsum[blockIdx.x] = sh[0];
}

__global__ __launch_bounds__(512) void k_scan_bsum(const int* __restrict__ bsum,
                                                   int* __restrict__ boff, int nb) {
  __shared__ int sh[512];
  int t = threadIdx.x;
  int v = (t < nb) ? bsum[t] : 0;
  sh[t] = v;
  __syncthreads();
  for (int s = 1; s < 512; s <<= 1) {
    int x = sh[t];
    int y = (t >= s) ? sh[t - s] : 0;
    __syncthreads();
    sh[t] = x + y;
    __syncthreads();
  }
  if (t < nb) boff[t] = sh[t] - v;  // exclusive
}

__global__ __launch_bounds__(TPB) void k_scan_final(const int* __restrict__ cnt,
                                                    const int* __restrict__ boff,
                                                    int* __restrict__ row_ptr, int N) {
  __shared__ int sh[TPB];
  int i = blockIdx.x * TPB + threadIdx.x;
  int t = threadIdx.x;
  int v = (i < N) ? cnt[i] : 0;
  sh[t] = v;
  __syncthreads();
  for (int s = 1; s < TPB; s <<= 1) {
    int x = sh[t];
    int y = (t >= s) ? sh[t - s] : 0;
    __syncthreads();
    sh[t] = x + y;
    __syncthreads();
  }
  if (i < N) row_ptr[i + 1] = boff[blockIdx.x] + sh[t];
  if (i == 0) row_ptr[0] = 0;
}

__global__ __launch_bounds__(TPB) void k_copy_int(const int* __restrict__ a,
                                                  int* __restrict__ b, int n) {
  int i = blockIdx.x * TPB + threadIdx.x;
  if (i < n) b[i] = a[i];
}

__global__ __launch_bounds__(TPB) void k_fill(const int* __restrict__ src,
                                              const int* __restrict__ dst,
                                              int* __restrict__ pos,
                                              int* __restrict__ col, int E) {
  int e = blockIdx.x * TPB + threadIdx.x;
  if (e < E) {
    int d = dst[e];
    int p = atomicAdd(&pos[d], 1);
    col[p] = src[e];
  }
}

// ---------------- GEMM ----------------
// Thread computes 1 row x 4 adjacent cols. W staged in LDS, read as float4
// (ds_read_b128 -> 4 FMAs per LDS instr). h row read as float4 from global
// (16B x few distinct addrs per wave, L1-resident across the block's rows).
// EPI 0: out = acc * dinv[row]                  (pre-aggregation scaling)
// EPI 1: out = relu(bn(acc + bias))             (post-aggregation layer-2 GEMM)
template <int FI, int FO, int EPI>
__global__ __launch_bounds__(TPB) void k_gemm(const float* __restrict__ h,
                                              const float* __restrict__ W,
                                              const float* __restrict__ dinv,
                                              const float* __restrict__ bias,
                                              const float* __restrict__ g,
                                              const float* __restrict__ be,
                                              const float* __restrict__ m,
                                              const float* __restrict__ v,
                                              float* __restrict__ out, int N) {
  __shared__ float Ws[FI * FO];
  for (int i = threadIdx.x; i < FI * FO / 4; i += TPB)
    reinterpret_cast<float4*>(Ws)[i] = reinterpret_cast<const float4*>(W)[i];
  __syncthreads();
  constexpr int CG = FO / 4;        // col groups of 4
  constexpr int RPB = TPB / CG;     // rows per block
  int row = blockIdx.x * RPB + (int)(threadIdx.x / CG);
  int cg = threadIdx.x % CG;
  if (row >= N) return;
  const float4* h4 = reinterpret_cast<const float4*>(h + (size_t)row * FI);
  float4 acc = {0.f, 0.f, 0.f, 0.f};
#pragma unroll
  for (int k4 = 0; k4 < FI / 4; ++k4) {
    float4 hv = h4[k4];
    float4 w0 = reinterpret_cast<const float4*>(&Ws[(4 * k4 + 0) * FO])[cg];
    float4 w1 = reinterpret_cast<const float4*>(&Ws[(4 * k4 + 1) * FO])[cg];
    float4 w2 = reinterpret_cast<const float4*>(&Ws[(4 * k4 + 2) * FO])[cg];
    float4 w3 = reinterpret_cast<const float4*>(&Ws[(4 * k4 + 3) * FO])[cg];
    acc.x = fmaf(hv.x, w0.x, acc.x); acc.y = fmaf(hv.x, w0.y, acc.y);
    acc.z = fmaf(hv.x, w0.z, acc.z); acc.w = fmaf(hv.x, w0.w, acc.w);
    acc.x = fmaf(hv.y, w1.x, acc.x); acc.y = fmaf(hv.y, w1.y, acc.y);
    acc.z = fmaf(hv.y, w1.z, acc.z); acc.w = fmaf(hv.y, w1.w, acc.w);
    acc.x = fmaf(hv.z, w2.x, acc.x); acc.y = fmaf(hv.z, w2.y, acc.y);
    acc.z = fmaf(hv.z, w2.z, acc.z); acc.w = fmaf(hv.z, w2.w, acc.w);
    acc.x = fmaf(hv.w, w3.x, acc.x); acc.y = fmaf(hv.w, w3.y, acc.y);
    acc.z = fmaf(hv.w, w3.z, acc.z); acc.w = fmaf(hv.w, w3.w, acc.w);
  }
  if (EPI == 0) {
    float dv = dinv[row];
    acc.x *= dv; acc.y *= dv; acc.z *= dv; acc.w *= dv;
  } else {
    float4 b4 = reinterpret_cast<const float4*>(bias)[cg];
    float4 g4 = reinterpret_cast<const float4*>(g)[cg];
    float4 e4 = reinterpret_cast<const float4*>(be)[cg];
    float4 m4 = reinterpret_cast<const float4*>(m)[cg];
    float4 v4 = reinterpret_cast<const float4*>(v)[cg];
    acc.x = fmaxf((acc.x + b4.x - m4.x) * (g4.x * rsqrtf(v4.x + BEPS)) + e4.x, 0.f);
    acc.y = fmaxf((acc.y + b4.y - m4.y) * (g4.y * rsqrtf(v4.y + BEPS)) + e4.y, 0.f);
    acc.z = fmaxf((acc.z + b4.z - m4.z) * (g4.z * rsqrtf(v4.z + BEPS)) + e4.z, 0.f);
    acc.w = fmaxf((acc.w + b4.w - m4.w) * (g4.w * rsqrtf(v4.w + BEPS)) + e4.w, 0.f);
  }
  reinterpret_cast<float4*>(out + (size_t)row * FO)[cg] = acc;
}

// ---------------- Aggregation ----------------
// Input rows are ALREADY scaled by dinv[src] (producer's epilogue). Computes
// val = dinv[node] * (sum_{s in N(node)} in[s] + in[node]), then:
// MODE 0: out = val + bias                       (final layer)
// MODE 1: out = relu(bn(val + bias))
// MODE 2: out = relu(bn(val + bias)) * dinv      (emit pre-scaled for next agg)
// MODE 3: out = val                              (pre-GEMM aggregation, layer 2)
// float4 lanes; edge loop unrolled 4x for 4 independent gathers in flight.
template <int F, int MODE>
__global__ __launch_bounds__(TPB) void k_agg(const float* __restrict__ in,
                                             const int* __restrict__ row_ptr,
                                             const int* __restrict__ colidx,
                                             const float* __restrict__ dinv,
                                             const float* __restrict__ bias,
                                             const float* __restrict__ g,
                                             const float* __restrict__ be,
                                             const float* __restrict__ m,
                                             const float* __restrict__ v,
                                             float* __restrict__ out, int N) {
  constexpr int V = F / 4;          // float4 lanes per node
  constexpr int NPB = TPB / V;      // nodes per block
  int node = blockIdx.x * NPB + (int)(threadIdx.x / V);
  int lane = threadIdx.x % V;
  if (node >= N) return;
  const float4* in4 = reinterpret_cast<const float4*>(in);
  float4 acc = in4[(size_t)node * V + lane];  // self-loop (pre-scaled)
  int e0 = row_ptr[node];
  int e1 = row_ptr[node + 1];
  int e = e0;
  for (; e + 4 <= e1; e += 4) {
    int s0 = colidx[e + 0];
    int s1 = colidx[e + 1];
    int s2 = colidx[e + 2];
    int s3 = colidx[e + 3];
    float4 a = in4[(size_t)s0 * V + lane];
    float4 b = in4[(size_t)s1 * V + lane];
    float4 c = in4[(size_t)s2 * V + lane];
    float4 d = in4[(size_t)s3 * V + lane];
    acc.x += a.x + b.x + c.x + d.x;
    acc.y += a.y + b.y + c.y + d.y;
    acc.z += a.z + b.z + c.z + d.z;
    acc.w += a.w + b.w + c.w + d.w;
  }
  for (; e < e1; ++e) {
    float4 a = in4[(size_t)colidx[e] * V + lane];
    acc.x += a.x; acc.y += a.y; acc.z += a.z; acc.w += a.w;
  }
  float dv = dinv[node];
  acc.x *= dv; acc.y *= dv; acc.z *= dv; acc.w *= dv;
  if (MODE == 0) {
    float4 b4 = reinterpret_cast<const float4*>(bias)[lane];
    acc.x += b4.x; acc.y += b4.y; acc.z += b4.z; acc.w += b4.w;
  } else if (MODE == 1 || MODE == 2) {
    float4 b4 = reinterpret_cast<const float4*>(bias)[lane];
    float4 g4 = reinterpret_cast<const float4*>(g)[lane];
    float4 e4 = reinterpret_cast<const float4*>(be)[lane];
    float4 m4 = reinterpret_cast<const float4*>(m)[lane];
    float4 v4 = reinterpret_cast<const float4*>(v)[lane];
    acc.x = fmaxf((acc.x + b4.x - m4.x) * (g4.x * rsqrtf(v4.x + BEPS)) + e4.x, 0.f);
    acc.y = fmaxf((acc.y + b4.y - m4.y) * (g4.y * rsqrtf(v4.y + BEPS)) + e4.y, 0.f);
    acc.z = fmaxf((acc.z + b4.z - m4.z) * (g4.z * rsqrtf(v4.z + BEPS)) + e4.z, 0.f);
    acc.w = fmaxf((acc.w + b4.w - m4.w) * (g4.w * rsqrtf(v4.w + BEPS)) + e4.w, 0.f);
    if (MODE == 2) { acc.x *= dv; acc.y *= dv; acc.z *= dv; acc.w *= dv; }
  }
  reinterpret_cast<float4*>(out)[(size_t)node * V + lane] = acc;
}

// ---------------- launch ----------------

extern "C" void kernel_launch(void* const* d_in, const int* in_sizes, int n_in,
                              void* d_out, int out_size, void* d_ws, size_t ws_size,
                              hipStream_t stream) {
  const float* x = (const float*)d_in[0];
  const int* ei = (const int*)d_in[1];
  const int N = in_sizes[0] / 128;
  const int E = in_sizes[1] / 2;
  const int* src = ei;
  const int* dst = ei + E;

  const float* w1 = (const float*)d_in[2];  const float* b1 = (const float*)d_in[3];
  const float* w2 = (const float*)d_in[4];  const float* b2 = (const float*)d_in[5];
  const float* w3 = (const float*)d_in[6];  const float* b3 = (const float*)d_in[7];
  const float* w4 = (const float*)d_in[8];  const float* b4 = (const float*)d_in[9];
  const float* w5 = (const float*)d_in[10]; const float* b5 = (const float*)d_in[11];
  const float* g1 = (const float*)d_in[12]; const float* be1 = (const float*)d_in[13];
  const float* m1 = (const float*)d_in[14]; const float* v1 = (const float*)d_in[15];
  const float* g2 = (const float*)d_in[16]; const float* be2 = (const float*)d_in[17];
  const float* m2 = (const float*)d_in[18]; const float* v2 = (const float*)d_in[19];
  const float* g3 = (const float*)d_in[20]; const float* be3 = (const float*)d_in[21];
  const float* m3 = (const float*)d_in[22]; const float* v3 = (const float*)d_in[23];
  const float* g4 = (const float*)d_in[24]; const float* be4 = (const float*)d_in[25];
  const float* m4 = (const float*)d_in[26]; const float* v4 = (const float*)d_in[27];
  float* out = (float*)d_out;

  char* ws = (char*)d_ws;
  size_t off = 0;
  auto alloc = [&](size_t bytes) -> void* {
    void* p = ws + off;
    off += (bytes + 255) & ~(size_t)255;
    return p;
  };
  float* dinv   = (float*)alloc((size_t)N * 4);
  int*   cnt    = (int*)  alloc((size_t)N * 4);
  int*   rowptr = (int*)  alloc((size_t)(N + 1) * 4);
  int*   bsum   = (int*)  alloc(512 * 4);
  int*   boff   = (int*)  alloc(512 * 4);
  int*   colidx = (int*)  alloc((size_t)E * 4);
  float* bufA   = (float*)alloc((size_t)N * 128 * 4);
  float* bufB   = (float*)alloc((size_t)N * 128 * 4);
  (void)ws_size; (void)n_in; (void)out_size;

  int gN = (N + TPB - 1) / TPB;
  int gE = (E + TPB - 1) / TPB;

  // CSR build
  k_zero_int<<<gN, TPB, 0, stream>>>(cnt, N);
  k_count<<<gE, TPB, 0, stream>>>(dst, cnt, E);
  k_dinv<<<gN, TPB, 0, stream>>>(cnt, dinv, N);
  k_blocksum<<<gN, TPB, 0, stream>>>(cnt, bsum, N);
  k_scan_bsum<<<1, 512, 0, stream>>>(bsum, boff, gN);
  k_scan_final<<<gN, TPB, 0, stream>>>(cnt, boff, rowptr, N);
  k_copy_int<<<gN, TPB, 0, stream>>>(rowptr, cnt, N);
  k_fill<<<gE, TPB, 0, stream>>>(src, dst, cnt, colidx, E);

  // L1: GEMM(128->64)*dinv, then AGG(64)+BN+ReLU, emit *dinv for L2's agg
  k_gemm<128, 64, 0><<<(N + 15) / 16, TPB, 0, stream>>>(x, w1, dinv, nullptr, nullptr, nullptr, nullptr, nullptr, bufB, N);
  k_agg<64, 2><<<(N + 15) / 16, TPB, 0, stream>>>(bufB, rowptr, colidx, dinv, b1, g1, be1, m1, v1, bufA, N);
  // L2: AGG(64) first (A(XW)=(AX)W), then GEMM(64->128)+bias+BN+ReLU
  k_agg<64, 3><<<(N + 15) / 16, TPB, 0, stream>>>(bufA, rowptr, colidx, dinv, nullptr, nullptr, nullptr, nullptr, nullptr, bufB, N);
  k_gemm<64, 128, 1><<<(N + 7) / 8, TPB, 0, stream>>>(bufB, w2, nullptr, b2, g2, be2, m2, v2, bufA, N);
  // L3: GEMM(128->64)*dinv, AGG(64)+BN+ReLU
  k_gemm<128, 64, 0><<<(N + 15) / 16, TPB, 0, stream>>>(bufA, w3, dinv, nullptr, nullptr, nullptr, nullptr, nullptr, bufB, N);
  k_agg<64, 1><<<(N + 15) / 16, TPB, 0, stream>>>(bufB, rowptr, colidx, dinv, b3, g3, be3, m3, v3, bufA, N);
  // L4: GEMM(64->32)*dinv, AGG(32)+BN+ReLU
  k_gemm<64, 32, 0><<<(N + 31) / 32, TPB, 0, stream>>>(bufA, w4, dinv, nullptr, nullptr, nullptr, nullptr, nullptr, bufB, N);
  k_agg<32, 1><<<(N + 31) / 32, TPB, 0, stream>>>(bufB, rowptr, colidx, dinv, b4, g4, be4, m4, v4, bufA, N);
  // L5: GEMM(32->16)*dinv, AGG(16)+bias -> out
  k_gemm<32, 16, 0><<<(N + 63) / 64, TPB, 0, stream>>>(bufA, w5, dinv, nullptr, nullptr, nullptr, nullptr, nullptr, bufB, N);
  k_agg<16, 0><<<(N + 63) / 64, TPB, 0, stream>>>(bufB, rowptr, colidx, dinv, b5, nullptr, nullptr, nullptr, nullptr, out, N);
}

// Round 3
// 465.339 us; speedup vs baseline: 3.2137x; 1.5048x over previous
//
#include <hip/hip_runtime.h>
#include <hip/hip_fp16.h>

#define BEPS 1e-5f
static constexpr int TPB = 256;
static constexpr int G_SC = 512;       // scatter workgroups
static constexpr int BK_SHIFT = 10;    // bucket = 1024-node range
static constexpr int BK_NODES = 1024;
static constexpr int KMAX = 128;       // max buckets (N <= 131072)

union F4H8 { float4 f4; __half2 h2[4]; };  // 16B = 8 halfs

// ================= CSR build: two-level bucket counting sort =================
// Replaces atomic-scatter k_fill (R2: 103MB WRITE_SIZE for 6.4MB of data, 16x
// line-write amplification from random 4B stores bouncing across XCD L2s).
// All global writes here are sequential-per-owner.

__global__ __launch_bounds__(TPB) void k_zero_int(int* __restrict__ p, int n) {
  int i = blockIdx.x * TPB + threadIdx.x;
  if (i < n) p[i] = 0;
}

// per-WG histogram over K buckets; also accumulate bucket totals
__global__ __launch_bounds__(TPB) void k_hist(const int* __restrict__ dst,
                                              int* __restrict__ histG,
                                              int* __restrict__ btot,
                                              int E, int K, int chunk) {
  __shared__ int lh[KMAX];
  int g = blockIdx.x, t = threadIdx.x;
  for (int i = t; i < K; i += TPB) lh[i] = 0;
  __syncthreads();
  int e0 = g * chunk, e1 = min(E, e0 + chunk);
  for (int e = e0 + t; e < e1; e += TPB) atomicAdd(&lh[dst[e] >> BK_SHIFT], 1);
  __syncthreads();
  for (int i = t; i < K; i += TPB) {
    histG[i * G_SC + g] = lh[i];
    atomicAdd(&btot[i], lh[i]);
  }
}

// exclusive scan of bucket totals -> bucket base offsets (bbase[K] = E)
__global__ __launch_bounds__(KMAX) void k_bbase(const int* __restrict__ btot,
                                                int* __restrict__ bbase, int K) {
  __shared__ int sh[KMAX];
  int t = threadIdx.x;
  int v = (t < K) ? btot[t] : 0;
  sh[t] = v;
  __syncthreads();
  for (int s = 1; s < KMAX; s <<= 1) {
    int x = sh[t];
    int y = (t >= s) ? sh[t - s] : 0;
    __syncthreads();
    sh[t] = x + y;
    __syncthreads();
  }
  if (t < K) bbase[t] = sh[t] - v;
  if (t == 0) bbase[K] = sh[K - 1];
}

// per-bucket exclusive scan over WGs -> private segment offsets offs[b][g]
__global__ __launch_bounds__(G_SC) void k_offs(const int* __restrict__ histG,
                                               const int* __restrict__ bbase,
                                               int* __restrict__ offs) {
  __shared__ int sh[G_SC];
  int b = blockIdx.x, t = threadIdx.x;
  int v = histG[b * G_SC + t];
  sh[t] = v;
  __syncthreads();
  for (int s = 1; s < G_SC; s <<= 1) {
    int x = sh[t];
    int y = (t >= s) ? sh[t - s] : 0;
    __syncthreads();
    sh[t] = x + y;
    __syncthreads();
  }
  offs[b * G_SC + t] = bbase[b] + sh[t] - v;
}

// scatter packed (src | dstLocal<<20) into per-(WG,bucket) private segments
__global__ __launch_bounds__(TPB) void k_scatter(const int* __restrict__ src,
                                                 const int* __restrict__ dst,
                                                 const int* __restrict__ offs,
                                                 unsigned int* __restrict__ pairs,
                                                 int E, int K, int chunk) {
  __shared__ int cur[KMAX];
  int g = blockIdx.x, t = threadIdx.x;
  for (int i = t; i < K; i += TPB) cur[i] = offs[i * G_SC + g];
  __syncthreads();
  int e0 = g * chunk, e1 = min(E, e0 + chunk);
  for (int e = e0 + t; e < e1; e += TPB) {
    int d = dst[e];
    int b = d >> BK_SHIFT;
    int pos = atomicAdd(&cur[b], 1);
    pairs[pos] = (unsigned int)src[e] | ((unsigned int)(d & (BK_NODES - 1)) << 20);
  }
}

// per-bucket LDS counting sort -> colidx (node-grouped), rowptr, dinv
__global__ __launch_bounds__(TPB) void k_bucket_sort(const unsigned int* __restrict__ pairs,
                                                     const int* __restrict__ bbase,
                                                     int* __restrict__ rowptr,
                                                     int* __restrict__ colidx,
                                                     float* __restrict__ dinv,
                                                     int N, int E) {
  __shared__ int deg[BK_NODES];
  __shared__ int excl[BK_NODES];
  __shared__ int s4[TPB];
  int b = blockIdx.x, t = threadIdx.x;
  int base = bbase[b], end = bbase[b + 1];
  int n0 = b << BK_SHIFT;
  int nNodes = min(BK_NODES, N - n0);
  for (int i = t; i < BK_NODES; i += TPB) deg[i] = 0;
  __syncthreads();
  for (int e = base + t; e < end; e += TPB) atomicAdd(&deg[pairs[e] >> 20], 1);
  __syncthreads();
  // exclusive scan of deg[0..1024): 4 elems/thread + Hillis-Steele over 256
  int a0 = deg[4 * t], a1 = deg[4 * t + 1], a2 = deg[4 * t + 2], a3 = deg[4 * t + 3];
  int tsum = a0 + a1 + a2 + a3;
  s4[t] = tsum;
  __syncthreads();
  for (int s = 1; s < TPB; s <<= 1) {
    int x = s4[t];
    int y = (t >= s) ? s4[t - s] : 0;
    __syncthreads();
    s4[t] = x + y;
    __syncthreads();
  }
  int texcl = s4[t] - tsum;
  excl[4 * t] = texcl;
  excl[4 * t + 1] = texcl + a0;
  excl[4 * t + 2] = texcl + a0 + a1;
  excl[4 * t + 3] = texcl + a0 + a1 + a2;
  __syncthreads();
  for (int i = t; i < nNodes; i += TPB) {
    rowptr[n0 + i] = base + excl[i];
    dinv[n0 + i] = rsqrtf((float)(deg[i] + 1));
  }
  if (b == (int)gridDim.x - 1 && t == 0) rowptr[N] = E;
  __syncthreads();
  for (int i = t; i < BK_NODES; i += TPB) deg[i] = excl[i];  // reuse as cursor
  __syncthreads();
  for (int e = base + t; e < end; e += TPB) {
    unsigned int p = pairs[e];
    int pos = atomicAdd(&deg[p >> 20], 1);
    colidx[base + pos] = (int)(p & 0xFFFFFu);
  }
}

// ================= GEMM: 4 rows x 4 cols per thread, W in LDS =================
// EPI 0: out = acc * dinv[row] (fp16)   EPI 1: out = relu(bn(acc + bias)) (fp16)
template <int FI, int FO, int EPI, bool HALF_IN>
__global__ __launch_bounds__(TPB) void k_gemm(const void* __restrict__ hin,
                                              const float* __restrict__ W,
                                              const float* __restrict__ dinv,
                                              const float* __restrict__ bias,
                                              const float* __restrict__ g,
                                              const float* __restrict__ be,
                                              const float* __restrict__ m,
                                              const float* __restrict__ v,
                                              __half* __restrict__ out, int N) {
  __shared__ float Ws[FI * FO];
  for (int i = threadIdx.x; i < FI * FO / 4; i += TPB)
    reinterpret_cast<float4*>(Ws)[i] = reinterpret_cast<const float4*>(W)[i];
  __syncthreads();
  constexpr int CG = FO / 4;
  constexpr int RG = TPB / CG;
  int rg = threadIdx.x / CG, cg = threadIdx.x % CG;
  int r0 = (blockIdx.x * RG + rg) * 4;  // N assumed %4==0
  if (r0 >= N) return;
  float acc[4][4] = {};
  if constexpr (!HALF_IN) {
    const float4* h4 = reinterpret_cast<const float4*>(hin);
    const size_t rs = FI / 4;
#pragma unroll
    for (int k4 = 0; k4 < FI / 4; ++k4) {
      float4 hr[4];
#pragma unroll
      for (int r = 0; r < 4; ++r) hr[r] = h4[(size_t)(r0 + r) * rs + k4];
#pragma unroll
      for (int j = 0; j < 4; ++j) {
        float4 w = reinterpret_cast<const float4*>(&Ws[(4 * k4 + j) * FO])[cg];
        float hj[4] = {j == 0 ? hr[0].x : j == 1 ? hr[0].y : j == 2 ? hr[0].z : hr[0].w,
                       j == 0 ? hr[1].x : j == 1 ? hr[1].y : j == 2 ? hr[1].z : hr[1].w,
                       j == 0 ? hr[2].x : j == 1 ? hr[2].y : j == 2 ? hr[2].z : hr[2].w,
                       j == 0 ? hr[3].x : j == 1 ? hr[3].y : j == 2 ? hr[3].z : hr[3].w};
#pragma unroll
        for (int r = 0; r < 4; ++r) {
          acc[r][0] = fmaf(hj[r], w.x, acc[r][0]);
          acc[r][1] = fmaf(hj[r], w.y, acc[r][1]);
          acc[r][2] = fmaf(hj[r], w.z, acc[r][2]);
          acc[r][3] = fmaf(hj[r], w.w, acc[r][3]);
        }
      }
    }
  } else {
    const float4* h8 = reinterpret_cast<const float4*>(hin);
    const size_t rs = FI / 8;
#pragma unroll
    for (int k8 = 0; k8 < FI / 8; ++k8) {
      float hr[4][8];
#pragma unroll
      for (int r = 0; r < 4; ++r) {
        F4H8 u;
        u.f4 = h8[(size_t)(r0 + r) * rs + k8];
#pragma unroll
        for (int i = 0; i < 4; ++i) {
          float2 t2 = __half22float2(u.h2[i]);
          hr[r][2 * i] = t2.x;
          hr[r][2 * i + 1] = t2.y;
        }
      }
#pragma unroll
      for (int j = 0; j < 8; ++j) {
        float4 w = reinterpret_cast<const float4*>(&Ws[(8 * k8 + j) * FO])[cg];
#pragma unroll
        for (int r = 0; r < 4; ++r) {
          acc[r][0] = fmaf(hr[r][j], w.x, acc[r][0]);
          acc[r][1] = fmaf(hr[r][j], w.y, acc[r][1]);
          acc[r][2] = fmaf(hr[r][j], w.z, acc[r][2]);
          acc[r][3] = fmaf(hr[r][j], w.w, acc[r][3]);
        }
      }
    }
  }
  float4 b4, g4, e4, m4, s4;
  if (EPI == 1) {
    b4 = reinterpret_cast<const float4*>(bias)[cg];
    g4 = reinterpret_cast<const float4*>(g)[cg];
    e4 = reinterpret_cast<const float4*>(be)[cg];
    m4 = reinterpret_cast<const float4*>(m)[cg];
    s4 = reinterpret_cast<const float4*>(v)[cg];
    s4.x = g4.x * rsqrtf(s4.x + BEPS); s4.y = g4.y * rsqrtf(s4.y + BEPS);
    s4.z = g4.z * rsqrtf(s4.z + BEPS); s4.w = g4.w * rsqrtf(s4.w + BEPS);
  }
#pragma unroll
  for (int r = 0; r < 4; ++r) {
    int row = r0 + r;
    float o0 = acc[r][0], o1 = acc[r][1], o2 = acc[r][2], o3 = acc[r][3];
    if (EPI == 0) {
      float dv = dinv[row];
      o0 *= dv; o1 *= dv; o2 *= dv; o3 *= dv;
    } else {
      o0 = fmaxf((o0 + b4.x - m4.x) * s4.x + e4.x, 0.f);
      o1 = fmaxf((o1 + b4.y - m4.y) * s4.y + e4.y, 0.f);
      o2 = fmaxf((o2 + b4.z - m4.z) * s4.z + e4.z, 0.f);
      o3 = fmaxf((o3 + b4.w - m4.w) * s4.w + e4.w, 0.f);
    }
    union { __half2 h2[2]; float2 f2; } u;
    u.h2[0] = __floats2half2_rn(o0, o1);
    u.h2[1] = __floats2half2_rn(o2, o3);
    reinterpret_cast<float2*>(out)[(size_t)row * (FO / 4) + cg] = u.f2;
  }
}

// ================= Aggregation (fp16 in, f32 accumulate) =================
// inputs pre-scaled by dinv[src]; val = dinv[node]*(sum_nbrs + self)
// MODE 0: val+bias (TO=float, final)  MODE 1: relu(bn(val+bias))
// MODE 2: relu(bn(val+bias))*dinv     MODE 3: val (pre-GEMM agg)
template <int F, int MODE, typename TO>
__global__ __launch_bounds__(TPB) void k_agg(const __half* __restrict__ in,
                                             const int* __restrict__ rowptr,
                                             const int* __restrict__ colidx,
                                             const float* __restrict__ dinv,
                                             const float* __restrict__ bias,
                                             const float* __restrict__ g,
                                             const float* __restrict__ be,
                                             const float* __restrict__ m,
                                             const float* __restrict__ v,
                                             TO* __restrict__ out, int N) {
  constexpr int V = F / 8;  // 16B (8-half) lanes per node
  constexpr int NPB = TPB / V;
  int node = blockIdx.x * NPB + (int)(threadIdx.x / V);
  int lane = threadIdx.x % V;
  if (node >= N) return;
  const float4* in16 = reinterpret_cast<const float4*>(in);
  const size_t rs = F / 8;
  float acc[8];
  {
    F4H8 u;
    u.f4 = in16[(size_t)node * rs + lane];
#pragma unroll
    for (int i = 0; i < 4; ++i) {
      float2 t2 = __half22float2(u.h2[i]);
      acc[2 * i] = t2.x;
      acc[2 * i + 1] = t2.y;
    }
  }
  int e0 = rowptr[node], e1 = rowptr[node + 1];
  int e = e0;
  for (; e + 4 <= e1; e += 4) {
    int s0 = colidx[e + 0], s1 = colidx[e + 1], s2 = colidx[e + 2], s3 = colidx[e + 3];
    F4H8 u0, u1, u2, u3;
    u0.f4 = in16[(size_t)s0 * rs + lane];
    u1.f4 = in16[(size_t)s1 * rs + lane];
    u2.f4 = in16[(size_t)s2 * rs + lane];
    u3.f4 = in16[(size_t)s3 * rs + lane];
#pragma unroll
    for (int i = 0; i < 4; ++i) {
      float2 a = __half22float2(u0.h2[i]), b = __half22float2(u1.h2[i]);
      float2 c = __half22float2(u2.h2[i]), d = __half22float2(u3.h2[i]);
      acc[2 * i] += (a.x + b.x) + (c.x + d.x);
      acc[2 * i + 1] += (a.y + b.y) + (c.y + d.y);
    }
  }
  for (; e < e1; ++e) {
    F4H8 u;
    u.f4 = in16[(size_t)colidx[e] * rs + lane];
#pragma unroll
    for (int i = 0; i < 4; ++i) {
      float2 t2 = __half22float2(u.h2[i]);
      acc[2 * i] += t2.x;
      acc[2 * i + 1] += t2.y;
    }
  }
  float dv = dinv[node];
#pragma unroll
  for (int i = 0; i < 8; ++i) acc[i] *= dv;
  if (MODE == 0) {
    float4 ba = reinterpret_cast<const float4*>(bias)[lane * 2];
    float4 bb = reinterpret_cast<const float4*>(bias)[lane * 2 + 1];
    acc[0] += ba.x; acc[1] += ba.y; acc[2] += ba.z; acc[3] += ba.w;
    acc[4] += bb.x; acc[5] += bb.y; acc[6] += bb.z; acc[7] += bb.w;
  } else if (MODE == 1 || MODE == 2) {
    const float4* B = reinterpret_cast<const float4*>(bias);
    const float4* G = reinterpret_cast<const float4*>(g);
    const float4* Be = reinterpret_cast<const float4*>(be);
    const float4* M = reinterpret_cast<const float4*>(m);
    const float4* Vv = reinterpret_cast<const float4*>(v);
#pragma unroll
    for (int h = 0; h < 2; ++h) {
      float4 b4 = B[lane * 2 + h], g4 = G[lane * 2 + h], e4 = Be[lane * 2 + h];
      float4 m4 = M[lane * 2 + h], v4 = Vv[lane * 2 + h];
      float* a = acc + 4 * h;
      a[0] = fmaxf((a[0] + b4.x - m4.x) * (g4.x * rsqrtf(v4.x + BEPS)) + e4.x, 0.f);
      a[1] = fmaxf((a[1] + b4.y - m4.y) * (g4.y * rsqrtf(v4.y + BEPS)) + e4.y, 0.f);
      a[2] = fmaxf((a[2] + b4.z - m4.z) * (g4.z * rsqrtf(v4.z + BEPS)) + e4.z, 0.f);
      a[3] = fmaxf((a[3] + b4.w - m4.w) * (g4.w * rsqrtf(v4.w + BEPS)) + e4.w, 0.f);
    }
    if (MODE == 2) {
#pragma unroll
      for (int i = 0; i < 8; ++i) acc[i] *= dv;
    }
  }
  if constexpr (sizeof(TO) == 2) {
    F4H8 u;
#pragma unroll
    for (int i = 0; i < 4; ++i) u.h2[i] = __floats2half2_rn(acc[2 * i], acc[2 * i + 1]);
    reinterpret_cast<float4*>(out)[(size_t)node * rs + lane] = u.f4;
  } else {
    float4 o0 = {acc[0], acc[1], acc[2], acc[3]};
    float4 o1 = {acc[4], acc[5], acc[6], acc[7]};
    float4* op = reinterpret_cast<float4*>((float*)out + (size_t)node * F + lane * 8);
    op[0] = o0;
    op[1] = o1;
  }
}

// ================= launch =================

extern "C" void kernel_launch(void* const* d_in, const int* in_sizes, int n_in,
                              void* d_out, int out_size, void* d_ws, size_t ws_size,
                              hipStream_t stream) {
  const float* x = (const float*)d_in[0];
  const int* ei = (const int*)d_in[1];
  const int N = in_sizes[0] / 128;
  const int E = in_sizes[1] / 2;
  const int* src = ei;
  const int* dst = ei + E;

  const float* w1 = (const float*)d_in[2];  const float* b1 = (const float*)d_in[3];
  const float* w2 = (const float*)d_in[4];  const float* b2 = (const float*)d_in[5];
  const float* w3 = (const float*)d_in[6];  const float* b3 = (const float*)d_in[7];
  const float* w4 = (const float*)d_in[8];  const float* b4 = (const float*)d_in[9];
  const float* w5 = (const float*)d_in[10]; const float* b5 = (const float*)d_in[11];
  const float* g1 = (const float*)d_in[12]; const float* be1 = (const float*)d_in[13];
  const float* m1 = (const float*)d_in[14]; const float* v1 = (const float*)d_in[15];
  const float* g2 = (const float*)d_in[16]; const float* be2 = (const float*)d_in[17];
  const float* m2 = (const float*)d_in[18]; const float* v2 = (const float*)d_in[19];
  const float* g3 = (const float*)d_in[20]; const float* be3 = (const float*)d_in[21];
  const float* m3 = (const float*)d_in[22]; const float* v3 = (const float*)d_in[23];
  const float* g4 = (const float*)d_in[24]; const float* be4 = (const float*)d_in[25];
  const float* m4 = (const float*)d_in[26]; const float* v4 = (const float*)d_in[27];
  float* out = (float*)d_out;

  char* ws = (char*)d_ws;
  size_t off = 0;
  auto alloc = [&](size_t bytes) -> void* {
    void* p = ws + off;
    off += (bytes + 255) & ~(size_t)255;
    return p;
  };
  float*        dinv   = (float*)alloc((size_t)N * 4);
  int*          rowptr = (int*)alloc((size_t)(N + 1) * 4);
  int*          colidx = (int*)alloc((size_t)E * 4);
  unsigned int* pairs  = (unsigned int*)alloc((size_t)E * 4);
  int*          histG  = (int*)alloc((size_t)KMAX * G_SC * 4);
  int*          offs   = (int*)alloc((size_t)KMAX * G_SC * 4);
  int*          btot   = (int*)alloc(KMAX * 4);
  int*          bbase  = (int*)alloc((KMAX + 1) * 4);
  __half*       bufA   = (__half*)alloc((size_t)N * 128 * 2);
  __half*       bufB   = (__half*)alloc((size_t)N * 128 * 2);
  (void)ws_size; (void)n_in; (void)out_size;

  const int K = (N + BK_NODES - 1) >> BK_SHIFT;  // 98 for N=100000 (<= KMAX)
  const int chunk = (E + G_SC - 1) / G_SC;

  // CSR build: hist -> bases -> per-WG offsets -> scatter -> bucket sort
  k_zero_int<<<1, TPB, 0, stream>>>(btot, KMAX);
  k_hist<<<G_SC, TPB, 0, stream>>>(dst, histG, btot, E, K, chunk);
  k_bbase<<<1, KMAX, 0, stream>>>(btot, bbase, K);
  k_offs<<<K, G_SC, 0, stream>>>(histG, bbase, offs);
  k_scatter<<<G_SC, TPB, 0, stream>>>(src, dst, offs, pairs, E, K, chunk);
  k_bucket_sort<<<K, TPB, 0, stream>>>(pairs, bbase, rowptr, colidx, dinv, N, E);

  // L1: GEMM(128->64)*dinv, AGG(64)+BN+ReLU emit *dinv for L2's agg
  k_gemm<128, 64, 0, false><<<(N + 63) / 64, TPB, 0, stream>>>(x, w1, dinv, nullptr, nullptr, nullptr, nullptr, nullptr, bufB, N);
  k_agg<64, 2, __half><<<(N + 31) / 32, TPB, 0, stream>>>(bufB, rowptr, colidx, dinv, b1, g1, be1, m1, v1, bufA, N);
  // L2: AGG(64) first, then GEMM(64->128)+bias+BN+ReLU
  k_agg<64, 3, __half><<<(N + 31) / 32, TPB, 0, stream>>>(bufA, rowptr, colidx, dinv, nullptr, nullptr, nullptr, nullptr, nullptr, bufB, N);
  k_gemm<64, 128, 1, true><<<(N + 31) / 32, TPB, 0, stream>>>(bufB, w2, nullptr, b2, g2, be2, m2, v2, bufA, N);
  // L3
  k_gemm<128, 64, 0, true><<<(N + 63) / 64, TPB, 0, stream>>>(bufA, w3, dinv, nullptr, nullptr, nullptr, nullptr, nullptr, bufB, N);
  k_agg<64, 1, __half><<<(N + 31) / 32, TPB, 0, stream>>>(bufB, rowptr, colidx, dinv, b3, g3, be3, m3, v3, bufA, N);
  // L4
  k_gemm<64, 32, 0, true><<<(N + 127) / 128, TPB, 0, stream>>>(bufA, w4, dinv, nullptr, nullptr, nullptr, nullptr, nullptr, bufB, N);
  k_agg<32, 1, __half><<<(N + 63) / 64, TPB, 0, stream>>>(bufB, rowptr, colidx, dinv, b4, g4, be4, m4, v4, bufA, N);
  // L5 -> f32 out
  k_gemm<32, 16, 0, true><<<(N + 255) / 256, TPB, 0, stream>>>(bufA, w5, dinv, nullptr, nullptr, nullptr, nullptr, nullptr, bufB, N);
  k_agg<16, 0, float><<<(N + 127) / 128, TPB, 0, stream>>>(bufB, rowptr, colidx, dinv, b5, nullptr, nullptr, nullptr, nullptr, out, N);
}

// Round 4
// 389.606 us; speedup vs baseline: 3.8384x; 1.1944x over previous
//
#include <hip/hip_runtime.h>
#include <hip/hip_fp16.h>

#define BEPS 1e-5f
static constexpr int TPB = 256;
static constexpr int G_SC = 512;      // scatter workgroups
static constexpr int BK_SHIFT = 8;    // bucket = 256-node range (R4: was 1024; 4x blocks)
static constexpr int BK_NODES = 256;
static constexpr int KMAX = 512;      // max buckets (N <= 131072)

union F4H8 { float4 f4; __half2 h2[4]; };  // 16B = 8 halfs

typedef _Float16 half8 __attribute__((ext_vector_type(8)));
typedef float floatx4 __attribute__((ext_vector_type(4)));

// ================= CSR build: two-level bucket counting sort =================

__global__ __launch_bounds__(TPB) void k_zero_int(int* __restrict__ p, int n) {
  int i = blockIdx.x * TPB + threadIdx.x;
  if (i < n) p[i] = 0;
}

__global__ __launch_bounds__(TPB) void k_hist(const int* __restrict__ dst,
                                              int* __restrict__ histG,
                                              int* __restrict__ btot,
                                              int E, int K, int chunk) {
  __shared__ int lh[KMAX];
  int g = blockIdx.x, t = threadIdx.x;
  for (int i = t; i < KMAX; i += TPB) lh[i] = 0;
  __syncthreads();
  int e0 = g * chunk, e1 = min(E, e0 + chunk);
  for (int e = e0 + t; e < e1; e += TPB) atomicAdd(&lh[dst[e] >> BK_SHIFT], 1);
  __syncthreads();
  for (int i = t; i < K; i += TPB) {
    histG[i * G_SC + g] = lh[i];
    atomicAdd(&btot[i], lh[i]);
  }
}

__global__ __launch_bounds__(KMAX) void k_bbase(const int* __restrict__ btot,
                                                int* __restrict__ bbase, int K) {
  __shared__ int sh[KMAX];
  int t = threadIdx.x;
  int v = (t < K) ? btot[t] : 0;
  sh[t] = v;
  __syncthreads();
  for (int s = 1; s < KMAX; s <<= 1) {
    int x = sh[t];
    int y = (t >= s) ? sh[t - s] : 0;
    __syncthreads();
    sh[t] = x + y;
    __syncthreads();
  }
  if (t < K) bbase[t] = sh[t] - v;
  if (t == 0) bbase[K] = sh[K - 1];
}

__global__ __launch_bounds__(G_SC) void k_offs(const int* __restrict__ histG,
                                               const int* __restrict__ bbase,
                                               int* __restrict__ offs) {
  __shared__ int sh[G_SC];
  int b = blockIdx.x, t = threadIdx.x;
  int v = histG[b * G_SC + t];
  sh[t] = v;
  __syncthreads();
  for (int s = 1; s < G_SC; s <<= 1) {
    int x = sh[t];
    int y = (t >= s) ? sh[t - s] : 0;
    __syncthreads();
    sh[t] = x + y;
    __syncthreads();
  }
  offs[b * G_SC + t] = bbase[b] + sh[t] - v;
}

__global__ __launch_bounds__(TPB) void k_scatter(const int* __restrict__ src,
                                                 const int* __restrict__ dst,
                                                 const int* __restrict__ offs,
                                                 unsigned int* __restrict__ pairs,
                                                 int E, int K, int chunk) {
  __shared__ int cur[KMAX];
  int g = blockIdx.x, t = threadIdx.x;
  for (int i = t; i < K; i += TPB) cur[i] = offs[i * G_SC + g];
  __syncthreads();
  int e0 = g * chunk, e1 = min(E, e0 + chunk);
  for (int e = e0 + t; e < e1; e += TPB) {
    int d = dst[e];
    int b = d >> BK_SHIFT;
    int pos = atomicAdd(&cur[b], 1);
    pairs[pos] = (unsigned int)src[e] | ((unsigned int)(d & (BK_NODES - 1)) << 20);
  }
}

// per-bucket LDS counting sort -> colidx (node-grouped), rowptr, dinv
__global__ __launch_bounds__(TPB) void k_bucket_sort(const unsigned int* __restrict__ pairs,
                                                     const int* __restrict__ bbase,
                                                     int* __restrict__ rowptr,
                                                     int* __restrict__ colidx,
                                                     float* __restrict__ dinv,
                                                     int N, int E) {
  __shared__ int deg[BK_NODES];
  __shared__ int sh[BK_NODES];
  int b = blockIdx.x, t = threadIdx.x;
  int base = bbase[b], end = bbase[b + 1];
  int n0 = b << BK_SHIFT;
  int nNodes = min(BK_NODES, N - n0);
  deg[t] = 0;
  __syncthreads();
  for (int e = base + t; e < end; e += TPB) atomicAdd(&deg[pairs[e] >> 20], 1);
  __syncthreads();
  int v = deg[t];
  sh[t] = v;
  __syncthreads();
  for (int s = 1; s < TPB; s <<= 1) {
    int x = sh[t];
    int y = (t >= s) ? sh[t - s] : 0;
    __syncthreads();
    sh[t] = x + y;
    __syncthreads();
  }
  int excl = sh[t] - v;
  if (t < nNodes) {
    rowptr[n0 + t] = base + excl;
    dinv[n0 + t] = rsqrtf((float)(v + 1));
  }
  if (b == (int)gridDim.x - 1 && t == 0) rowptr[N] = E;
  __syncthreads();
  deg[t] = excl;  // reuse as cursor
  __syncthreads();
  for (int e = base + t; e < end; e += TPB) {
    unsigned int p = pairs[e];
    int pos = atomicAdd(&deg[p >> 20], 1);
    colidx[base + pos] = (int)(p & 0xFFFFFu);
  }
}

// ================= W pack: fp32 W[K][FO] -> fp16 B-fragment layout =================
// Wp flat index i: j=i&7, lane=(i>>3)&63, tile=i>>9; ct=tile%(FO/16), kch=tile/(FO/16)
// value = W[kch*32 + (lane>>4)*8 + j][ct*16 + (lane&15)]
__global__ __launch_bounds__(TPB) void k_packW(const float* __restrict__ W,
                                               _Float16* __restrict__ Wp,
                                               int K, int FO) {
  int i = blockIdx.x * TPB + threadIdx.x;
  if (i >= K * FO) return;
  int j = i & 7;
  int lane = (i >> 3) & 63;
  int tile = i >> 9;
  int nct = FO >> 4;
  int ct = tile % nct, kch = tile / nct;
  int k = kch * 32 + ((lane >> 4) << 3) + j;
  int n = (ct << 4) + (lane & 15);
  Wp[i] = (_Float16)W[k * FO + n];
}

// ================= MFMA GEMM =================
// Block = 4 waves; wave computes 16 rows x FO via v_mfma_f32_16x16x32_f16.
// A-frag: m=lane&15, k=quad*8+j.  B-frag (pre-packed): n=lane&15, k=quad*8+j.
// C/D: col=lane&15, row=quad*4+reg.
// EPI 0: out = acc*dinv[row] (fp16)   EPI 1: out = relu(bn(acc+bias)) (fp16)
template <int FI, int FO, int EPI, bool F32IN>
__global__ __launch_bounds__(TPB) void k_mgemm(const void* __restrict__ hin,
                                               const _Float16* __restrict__ Wp,
                                               const float* __restrict__ dinv,
                                               const float* __restrict__ bias,
                                               const float* __restrict__ g,
                                               const float* __restrict__ be,
                                               const float* __restrict__ m,
                                               const float* __restrict__ v,
                                               __half* __restrict__ out, int N) {
  constexpr int NCT = FO / 16;   // col tiles
  constexpr int NKC = FI / 32;   // k chunks
  __shared__ float4 Wsh[NKC * NCT * 64];  // FI*FO*2 bytes
  for (int i = threadIdx.x; i < NKC * NCT * 64; i += TPB)
    Wsh[i] = reinterpret_cast<const float4*>(Wp)[i];
  __syncthreads();

  int lane = threadIdx.x & 63;
  int wv = threadIdx.x >> 6;
  int quad = lane >> 4;
  int rowBase = blockIdx.x * 64 + wv * 16;
  int rA = min(rowBase + (lane & 15), N - 1);

  floatx4 acc[NCT];
#pragma unroll
  for (int ct = 0; ct < NCT; ++ct) acc[ct] = (floatx4){0.f, 0.f, 0.f, 0.f};

#pragma unroll
  for (int kch = 0; kch < NKC; ++kch) {
    half8 a;
    if constexpr (F32IN) {
      const float4* xp = reinterpret_cast<const float4*>(hin);
      size_t idx = ((size_t)rA * FI + kch * 32 + quad * 8) >> 2;
      float4 fa = xp[idx], fb = xp[idx + 1];
      a[0] = (_Float16)fa.x; a[1] = (_Float16)fa.y; a[2] = (_Float16)fa.z; a[3] = (_Float16)fa.w;
      a[4] = (_Float16)fb.x; a[5] = (_Float16)fb.y; a[6] = (_Float16)fb.z; a[7] = (_Float16)fb.w;
    } else {
      union { float4 f4; half8 h8; } ua;
      ua.f4 = reinterpret_cast<const float4*>(hin)[((size_t)rA * FI + kch * 32 + quad * 8) >> 3];
      a = ua.h8;
    }
#pragma unroll
    for (int ct = 0; ct < NCT; ++ct) {
      union { float4 f4; half8 h8; } ub;
      ub.f4 = Wsh[(kch * NCT + ct) * 64 + lane];
      acc[ct] = __builtin_amdgcn_mfma_f32_16x16x32_f16(a, ub.h8, acc[ct], 0, 0, 0);
    }
  }

  int r0 = rowBase + quad * 4;
  if (EPI == 0) {
    float dv[4];
#pragma unroll
    for (int reg = 0; reg < 4; ++reg) dv[reg] = (r0 + reg < N) ? dinv[r0 + reg] : 0.f;
#pragma unroll
    for (int ct = 0; ct < NCT; ++ct) {
      int col = ct * 16 + (lane & 15);
#pragma unroll
      for (int reg = 0; reg < 4; ++reg) {
        int r = r0 + reg;
        if (r < N) out[(size_t)r * FO + col] = __float2half(acc[ct][reg] * dv[reg]);
      }
    }
  } else {
#pragma unroll
    for (int ct = 0; ct < NCT; ++ct) {
      int col = ct * 16 + (lane & 15);
      float sc = g[col] * rsqrtf(v[col] + BEPS);
      float bb = bias[col] - m[col];
      float ee = be[col];
#pragma unroll
      for (int reg = 0; reg < 4; ++reg) {
        int r = r0 + reg;
        if (r < N) out[(size_t)r * FO + col] = __float2half(fmaxf((acc[ct][reg] + bb) * sc + ee, 0.f));
      }
    }
  }
}

// ================= Aggregation (fp16 in, f32 accumulate) =================
// MODE 0: val+bias (TO=float, final)  MODE 1: relu(bn(val+bias))
// MODE 2: relu(bn(val+bias))*dinv     MODE 3: val (pre-GEMM agg)
template <int F, int MODE, typename TO>
__global__ __launch_bounds__(TPB) void k_agg(const __half* __restrict__ in,
                                             const int* __restrict__ rowptr,
                                             const int* __restrict__ colidx,
                                             const float* __restrict__ dinv,
                                             const float* __restrict__ bias,
                                             const float* __restrict__ g,
                                             const float* __restrict__ be,
                                             const float* __restrict__ m,
                                             const float* __restrict__ v,
                                             TO* __restrict__ out, int N) {
  constexpr int V = F / 8;
  constexpr int NPB = TPB / V;
  int node = blockIdx.x * NPB + (int)(threadIdx.x / V);
  int lane = threadIdx.x % V;
  if (node >= N) return;
  const float4* in16 = reinterpret_cast<const float4*>(in);
  const size_t rs = F / 8;
  float acc[8];
  {
    F4H8 u;
    u.f4 = in16[(size_t)node * rs + lane];
#pragma unroll
    for (int i = 0; i < 4; ++i) {
      float2 t2 = __half22float2(u.h2[i]);
      acc[2 * i] = t2.x;
      acc[2 * i + 1] = t2.y;
    }
  }
  int e0 = rowptr[node], e1 = rowptr[node + 1];
  int e = e0;
  for (; e + 4 <= e1; e += 4) {
    int s0 = colidx[e + 0], s1 = colidx[e + 1], s2 = colidx[e + 2], s3 = colidx[e + 3];
    F4H8 u0, u1, u2, u3;
    u0.f4 = in16[(size_t)s0 * rs + lane];
    u1.f4 = in16[(size_t)s1 * rs + lane];
    u2.f4 = in16[(size_t)s2 * rs + lane];
    u3.f4 = in16[(size_t)s3 * rs + lane];
#pragma unroll
    for (int i = 0; i < 4; ++i) {
      float2 a = __half22float2(u0.h2[i]), b = __half22float2(u1.h2[i]);
      float2 c = __half22float2(u2.h2[i]), d = __half22float2(u3.h2[i]);
      acc[2 * i] += (a.x + b.x) + (c.x + d.x);
      acc[2 * i + 1] += (a.y + b.y) + (c.y + d.y);
    }
  }
  for (; e < e1; ++e) {
    F4H8 u;
    u.f4 = in16[(size_t)colidx[e] * rs + lane];
#pragma unroll
    for (int i = 0; i < 4; ++i) {
      float2 t2 = __half22float2(u.h2[i]);
      acc[2 * i] += t2.x;
      acc[2 * i + 1] += t2.y;
    }
  }
  float dv = dinv[node];
#pragma unroll
  for (int i = 0; i < 8; ++i) acc[i] *= dv;
  if (MODE == 0) {
    float4 ba = reinterpret_cast<const float4*>(bias)[lane * 2];
    float4 bb = reinterpret_cast<const float4*>(bias)[lane * 2 + 1];
    acc[0] += ba.x; acc[1] += ba.y; acc[2] += ba.z; acc[3] += ba.w;
    acc[4] += bb.x; acc[5] += bb.y; acc[6] += bb.z; acc[7] += bb.w;
  } else if (MODE == 1 || MODE == 2) {
    const float4* B = reinterpret_cast<const float4*>(bias);
    const float4* G = reinterpret_cast<const float4*>(g);
    const float4* Be = reinterpret_cast<const float4*>(be);
    const float4* M = reinterpret_cast<const float4*>(m);
    const float4* Vv = reinterpret_cast<const float4*>(v);
#pragma unroll
    for (int h = 0; h < 2; ++h) {
      float4 b4 = B[lane * 2 + h], g4 = G[lane * 2 + h], e4 = Be[lane * 2 + h];
      float4 m4 = M[lane * 2 + h], v4 = Vv[lane * 2 + h];
      float* a = acc + 4 * h;
      a[0] = fmaxf((a[0] + b4.x - m4.x) * (g4.x * rsqrtf(v4.x + BEPS)) + e4.x, 0.f);
      a[1] = fmaxf((a[1] + b4.y - m4.y) * (g4.y * rsqrtf(v4.y + BEPS)) + e4.y, 0.f);
      a[2] = fmaxf((a[2] + b4.z - m4.z) * (g4.z * rsqrtf(v4.z + BEPS)) + e4.z, 0.f);
      a[3] = fmaxf((a[3] + b4.w - m4.w) * (g4.w * rsqrtf(v4.w + BEPS)) + e4.w, 0.f);
    }
    if (MODE == 2) {
#pragma unroll
      for (int i = 0; i < 8; ++i) acc[i] *= dv;
    }
  }
  if constexpr (sizeof(TO) == 2) {
    F4H8 u;
#pragma unroll
    for (int i = 0; i < 4; ++i) u.h2[i] = __floats2half2_rn(acc[2 * i], acc[2 * i + 1]);
    reinterpret_cast<float4*>(out)[(size_t)node * rs + lane] = u.f4;
  } else {
    float4 o0 = {acc[0], acc[1], acc[2], acc[3]};
    float4 o1 = {acc[4], acc[5], acc[6], acc[7]};
    float4* op = reinterpret_cast<float4*>((float*)out + (size_t)node * F + lane * 8);
    op[0] = o0;
    op[1] = o1;
  }
}

// ================= launch =================

extern "C" void kernel_launch(void* const* d_in, const int* in_sizes, int n_in,
                              void* d_out, int out_size, void* d_ws, size_t ws_size,
                              hipStream_t stream) {
  const float* x = (const float*)d_in[0];
  const int* ei = (const int*)d_in[1];
  const int N = in_sizes[0] / 128;
  const int E = in_sizes[1] / 2;
  const int* src = ei;
  const int* dst = ei + E;

  const float* w1 = (const float*)d_in[2];  const float* b1 = (const float*)d_in[3];
  const float* w2 = (const float*)d_in[4];  const float* b2 = (const float*)d_in[5];
  const float* w3 = (const float*)d_in[6];  const float* b3 = (const float*)d_in[7];
  const float* w4 = (const float*)d_in[8];  const float* b4 = (const float*)d_in[9];
  const float* w5 = (const float*)d_in[10]; const float* b5 = (const float*)d_in[11];
  const float* g1 = (const float*)d_in[12]; const float* be1 = (const float*)d_in[13];
  const float* m1 = (const float*)d_in[14]; const float* v1 = (const float*)d_in[15];
  const float* g2 = (const float*)d_in[16]; const float* be2 = (const float*)d_in[17];
  const float* m2 = (const float*)d_in[18]; const float* v2 = (const float*)d_in[19];
  const float* g3 = (const float*)d_in[20]; const float* be3 = (const float*)d_in[21];
  const float* m3 = (const float*)d_in[22]; const float* v3 = (const float*)d_in[23];
  const float* g4 = (const float*)d_in[24]; const float* be4 = (const float*)d_in[25];
  const float* m4 = (const float*)d_in[26]; const float* v4 = (const float*)d_in[27];
  float* out = (float*)d_out;

  char* ws = (char*)d_ws;
  size_t off = 0;
  auto alloc = [&](size_t bytes) -> void* {
    void* p = ws + off;
    off += (bytes + 255) & ~(size_t)255;
    return p;
  };
  float*        dinv   = (float*)alloc((size_t)N * 4);
  int*          rowptr = (int*)alloc((size_t)(N + 1) * 4);
  int*          colidx = (int*)alloc((size_t)E * 4);
  unsigned int* pairs  = (unsigned int*)alloc((size_t)E * 4);
  int*          histG  = (int*)alloc((size_t)KMAX * G_SC * 4);
  int*          offs   = (int*)alloc((size_t)KMAX * G_SC * 4);
  int*          btot   = (int*)alloc(KMAX * 4);
  int*          bbase  = (int*)alloc((KMAX + 1) * 4);
  _Float16*     wp1    = (_Float16*)alloc(128 * 64 * 2);
  _Float16*     wp2    = (_Float16*)alloc(64 * 128 * 2);
  _Float16*     wp3    = (_Float16*)alloc(128 * 64 * 2);
  _Float16*     wp4    = (_Float16*)alloc(64 * 32 * 2);
  _Float16*     wp5    = (_Float16*)alloc(32 * 16 * 2);
  __half*       bufA   = (__half*)alloc((size_t)N * 128 * 2);
  __half*       bufB   = (__half*)alloc((size_t)N * 128 * 2);
  (void)ws_size; (void)n_in; (void)out_size;

  const int K = (N + BK_NODES - 1) >> BK_SHIFT;  // 391 for N=100000
  const int chunk = (E + G_SC - 1) / G_SC;

  // CSR build
  k_zero_int<<<2, TPB, 0, stream>>>(btot, KMAX);
  k_hist<<<G_SC, TPB, 0, stream>>>(dst, histG, btot, E, K, chunk);
  k_bbase<<<1, KMAX, 0, stream>>>(btot, bbase, K);
  k_offs<<<K, G_SC, 0, stream>>>(histG, bbase, offs);
  k_scatter<<<G_SC, TPB, 0, stream>>>(src, dst, offs, pairs, E, K, chunk);
  k_bucket_sort<<<K, TPB, 0, stream>>>(pairs, bbase, rowptr, colidx, dinv, N, E);

  // pack weights into MFMA B-fragment layout (tiny)
  k_packW<<<(128 * 64 + TPB - 1) / TPB, TPB, 0, stream>>>(w1, wp1, 128, 64);
  k_packW<<<(64 * 128 + TPB - 1) / TPB, TPB, 0, stream>>>(w2, wp2, 64, 128);
  k_packW<<<(128 * 64 + TPB - 1) / TPB, TPB, 0, stream>>>(w3, wp3, 128, 64);
  k_packW<<<(64 * 32 + TPB - 1) / TPB, TPB, 0, stream>>>(w4, wp4, 64, 32);
  k_packW<<<(32 * 16 + TPB - 1) / TPB, TPB, 0, stream>>>(w5, wp5, 32, 16);

  int gRow = (N + 63) / 64;
  // L1: MFMA GEMM(128->64)*dinv, AGG(64)+BN+ReLU emit *dinv for L2's agg
  k_mgemm<128, 64, 0, true><<<gRow, TPB, 0, stream>>>(x, wp1, dinv, nullptr, nullptr, nullptr, nullptr, nullptr, bufB, N);
  k_agg<64, 2, __half><<<(N + 31) / 32, TPB, 0, stream>>>(bufB, rowptr, colidx, dinv, b1, g1, be1, m1, v1, bufA, N);
  // L2: AGG(64) first, then MFMA GEMM(64->128)+bias+BN+ReLU
  k_agg<64, 3, __half><<<(N + 31) / 32, TPB, 0, stream>>>(bufA, rowptr, colidx, dinv, nullptr, nullptr, nullptr, nullptr, nullptr, bufB, N);
  k_mgemm<64, 128, 1, false><<<gRow, TPB, 0, stream>>>(bufB, wp2, nullptr, b2, g2, be2, m2, v2, bufA, N);
  // L3
  k_mgemm<128, 64, 0, false><<<gRow, TPB, 0, stream>>>(bufA, wp3, dinv, nullptr, nullptr, nullptr, nullptr, nullptr, bufB, N);
  k_agg<64, 1, __half><<<(N + 31) / 32, TPB, 0, stream>>>(bufB, rowptr, colidx, dinv, b3, g3, be3, m3, v3, bufA, N);
  // L4
  k_mgemm<64, 32, 0, false><<<gRow, TPB, 0, stream>>>(bufA, wp4, dinv, nullptr, nullptr, nullptr, nullptr, nullptr, bufB, N);
  k_agg<32, 1, __half><<<(N + 63) / 64, TPB, 0, stream>>>(bufB, rowptr, colidx, dinv, b4, g4, be4, m4, v4, bufA, N);
  // L5 -> f32 out
  k_mgemm<32, 16, 0, false><<<gRow, TPB, 0, stream>>>(bufA, wp5, dinv, nullptr, nullptr, nullptr, nullptr, nullptr, bufB, N);
  k_agg<16, 0, float><<<(N + 127) / 128, TPB, 0, stream>>>(bufB, rowptr, colidx, dinv, b5, nullptr, nullptr, nullptr, nullptr, out, N);
}